// Round 9
// baseline (87.607 us; speedup 1.0000x reference)
//
#include <hip/hip_runtime.h>
#include <hip/hip_bf16.h>
#include <math.h>

#define NEG 0.1f
#define EPSV 1e-8f

constexpr int D = 1024;
constexpr int KTILES = 16;    // K-tiles of 64

typedef __bf16 bf16x8 __attribute__((ext_vector_type(8)));
typedef float  f32x4  __attribute__((ext_vector_type(4)));

__device__ __forceinline__ bf16x8 cvt8(float4 a, float4 b) {
    bf16x8 r;
    r[0] = (__bf16)a.x; r[1] = (__bf16)a.y; r[2] = (__bf16)a.z; r[3] = (__bf16)a.w;
    r[4] = (__bf16)b.x; r[5] = (__bf16)b.y; r[6] = (__bf16)b.z; r[7] = (__bf16)b.w;
    return r;
}

// async global->LDS, 16B/lane; LDS dest = wave-uniform base + lane*16
__device__ __forceinline__ void gld_lds16(const __bf16* g, __bf16* l) {
    __builtin_amdgcn_global_load_lds(
        (__attribute__((address_space(1))) void*)(size_t)(const void*)g,
        (__attribute__((address_space(3))) void*)l,
        16, 0, 0);
}

// ---------- W convert (pre-swizzle) + cap partial sums ----------
// blocks [0,1024): W f32 -> bf16, dst slot s holds orig slot s^(e&7)
// blocks [1024,1536): cap partial sums per (c, quarter) -> cappart
__global__ __launch_bounds__(256)
void convert_wcap(const float* __restrict__ Wvt, const float* __restrict__ Wvi,
                  const float* __restrict__ cap, const int* __restrict__ lens,
                  __bf16* __restrict__ wtb, __bf16* __restrict__ wib,
                  float* __restrict__ cappart)
{
    const int bid = blockIdx.x;
    if (bid < 1024) {
        int g = bid * 256 + threadIdx.x;          // 262144 slot tasks
        const float* src = (g < 131072) ? Wvt : Wvi;
        __bf16*      dst = (g < 131072) ? wtb : wib;
        g &= 131071;
        const int e  = g >> 7;
        const int sl = g & 127;
        const int c  = sl >> 3, si = sl & 7;
        const int ss = (c << 3) | (si ^ (e & 7));
        const float* p = src + (size_t)e * D + ss * 8;
        *(bf16x8*)(dst + (size_t)e * D + sl * 8) =
            cvt8(*(const float4*)p, *(const float4*)(p + 4));
    } else {
        const int cb = bid - 1024;                // 0..511
        const int c = cb >> 2, q = cb & 3;
        const int col = threadIdx.x * 4;
        const int len = lens[c];
        const float* src = cap + (size_t)c * 64 * D + col;
        float4 acc = make_float4(0.f, 0.f, 0.f, 0.f);
        #pragma unroll
        for (int tt = 0; tt < 16; ++tt) {
            const int t = q * 16 + tt;
            if (t < len) {
                float4 v = *(const float4*)(src + (size_t)t * D);
                acc.x += v.x; acc.y += v.y; acc.z += v.z; acc.w += v.w;
            }
        }
        *(float4*)(cappart + ((size_t)q * 128 + c) * D + col) = acc;
    }
}

// cap_vec[c] = l2norm( (sum_q part[q][c]) / len )
__global__ __launch_bounds__(256)
void capfin(const float* __restrict__ cappart, const int* __restrict__ lens,
            float* __restrict__ capv)
{
    const int c = blockIdx.x, tid = threadIdx.x;
    const int col = tid * 4;
    float4 acc = make_float4(0.f, 0.f, 0.f, 0.f);
    #pragma unroll
    for (int q = 0; q < 4; ++q) {
        float4 v = *(const float4*)(cappart + ((size_t)q * 128 + c) * D + col);
        acc.x += v.x; acc.y += v.y; acc.z += v.z; acc.w += v.w;
    }
    const float inv = 1.f / (float)lens[c];
    acc.x *= inv; acc.y *= inv; acc.z *= inv; acc.w *= inv;
    float ss = acc.x * acc.x + acc.y * acc.y + acc.z * acc.z + acc.w * acc.w;
    #pragma unroll
    for (int o = 32; o > 0; o >>= 1) ss += __shfl_xor(ss, o, 64);
    __shared__ float wsum[4];
    if ((tid & 63) == 0) wsum[tid >> 6] = ss;
    __syncthreads();
    const float total = wsum[0] + wsum[1] + wsum[2] + wsum[3];
    const float r = 1.f / (sqrtf(total) + EPSV);
    float4 o4 = make_float4(acc.x * r, acc.y * r, acc.z * r, acc.w * r);
    *(float4*)(capv + (size_t)c * D + col) = o4;
}

// ---------- 8-wave 256x256 GEMM, 8-phase, A reg-staged from f32 ----------
// out[b][e] = scale * sum_{t<lb[b]} leaky( dot(A[b][t][:], W[e][:]) + bias[e] )
// A: original f32 (cap [128][64][D] or img [128][36][D]); staged per tile:
//   p0 issue 8 dwordx4 -> regs; p3 vmcnt(0) -> cvt -> 4 swizzled ds_write_b128.
// W: bf16 pre-swizzled, global_load_lds. Unstaged LDS rows are garbage but each
// MFMA output row depends only on its own A row; epilogue masks t<lb.
template<bool IMG>
__device__ __forceinline__ void gemm_body(
    const float* __restrict__ Asrc, const __bf16* __restrict__ Wsw,
    const float* __restrict__ bias, const int* __restrict__ lens,
    float scale, float* __restrict__ out, int mb, int nb, __bf16* sm)
{
    __bf16* A0 = sm;              // [256][64] bf16
    __bf16* A1 = sm + 16384;
    __bf16* B0 = sm + 32768;
    __bf16* B1 = sm + 49152;

    const int tid  = threadIdx.x;
    const int wid  = tid >> 6;     // 0..7
    const int lane = tid & 63;
    const int r16  = lane & 15;
    const int kg   = lane >> 4;
    const int wm   = wid >> 2;     // 0..1
    const int wn   = wid & 3;      // 0..3
    const int e0   = nb * 256;
    const int bglobal = mb * 4;
    const int SR = IMG ? 36 : 64;  // source rows per batch

    int lb[2];
    #pragma unroll
    for (int g = 0; g < 2; ++g) {
        const int b = bglobal + wm * 2 + g;
        lb[g] = IMG ? 36 : (lens[b] < 64 ? lens[b] : 64);
    }
    bool mact[8];
    #pragma unroll
    for (int mi = 0; mi < 8; ++mi)
        mact[mi] = ((mi & 3) * 16) < lb[mi >> 2];

    // ---- B staging: 4 gload_lds/wave/tile, linear LDS (pre-swizzled source) ----
    const __bf16* bS = Wsw + (size_t)(e0 + wid * 32 + (lane >> 3)) * D + (lane & 7) * 8;
    const int bDst = wid * 2048;
    auto stageB = [&](int kt, __bf16* Bd) {
        #pragma unroll
        for (int c = 0; c < 4; ++c)
            gld_lds16(bS + (size_t)c * 8 * D + kt * 64, Bd + bDst + c * 512);
    };

    // ---- A reg staging: lane owns (row = wid*32 + lane>>1, half = lane&1) ----
    const int arow    = wid * 32 + (lane >> 1);        // block-local row
    const int half    = lane & 1;
    const int t_row   = (wid & 1) * 32 + (lane >> 1);  // row within batch
    const int batch_l = wid >> 1;                      // 0..3
    const int rlv     = IMG ? 36
                            : (lens[bglobal + batch_l] < 64 ? lens[bglobal + batch_l] : 64);
    const bool alive  = t_row < rlv;
    const float* aR = Asrc + ((size_t)(bglobal + batch_l) * SR + (alive ? t_row : 0)) * D
                    + half * 32;
    int woff[4];
    #pragma unroll
    for (int s = 0; s < 4; ++s)
        woff[s] = arow * 64 + (((half * 4 + s) ^ (arow & 7)) << 3);

    float4 fA[8];
    auto loadA = [&](int kt) {
        if (alive) {
            #pragma unroll
            for (int c = 0; c < 8; ++c)
                fA[c] = *(const float4*)(aR + kt * 64 + c * 4);
        }
    };
    auto writeA = [&](__bf16* Ad) {
        if (alive) {
            #pragma unroll
            for (int s = 0; s < 4; ++s)
                *(bf16x8*)&Ad[woff[s]] = cvt8(fA[2 * s], fA[2 * s + 1]);
        }
    };

    f32x4 acc[8][4];
    #pragma unroll
    for (int mi = 0; mi < 8; ++mi)
        #pragma unroll
        for (int ni = 0; ni < 4; ++ni)
            acc[mi][ni] = (f32x4){0.f, 0.f, 0.f, 0.f};

    const int swk = r16 & 7;
    const int sk0 = ((0 + kg) ^ swk) << 3;
    const int sk1 = ((4 + kg) ^ swk) << 3;
    const int aBase = (wm * 128 + r16) * 64;
    const int bBase = (wn * 64 + r16) * 64;

    auto tile = [&](int t, __bf16* Ac, __bf16* Bc, __bf16* An, __bf16* Bn) {
        const bool more = (t + 1) < KTILES;
        bf16x8 bf[4][2];
        #pragma unroll
        for (int p = 0; p < 4; ++p) {
            if (p == 0) {
                #pragma unroll
                for (int ni = 0; ni < 4; ++ni) {
                    bf[ni][0] = *(const bf16x8*)&Bc[bBase + ni * 1024 + sk0];
                    bf[ni][1] = *(const bf16x8*)&Bc[bBase + ni * 1024 + sk1];
                }
            }
            bf16x8 af[2][2];
            const bool act0 = mact[2 * p];
            const bool act1 = mact[2 * p + 1];
            if (act0) {
                af[0][0] = *(const bf16x8*)&Ac[aBase + (2 * p) * 1024 + sk0];
                af[0][1] = *(const bf16x8*)&Ac[aBase + (2 * p) * 1024 + sk1];
            }
            if (act1) {
                af[1][0] = *(const bf16x8*)&Ac[aBase + (2 * p + 1) * 1024 + sk0];
                af[1][1] = *(const bf16x8*)&Ac[aBase + (2 * p + 1) * 1024 + sk1];
            }
            // issue next tile's staging early (T14): B->LDS async, A->regs
            if (more && p == 0) { stageB(t + 1, Bn); loadA(t + 1); }
            // once per tile: drain (issued 3 phases ago), then write A(next)
            if (p == 3) {
                asm volatile("s_waitcnt vmcnt(0)" ::: "memory");
                if (more) writeA(An);
            }
            __builtin_amdgcn_s_barrier();
            asm volatile("s_waitcnt lgkmcnt(0)" ::: "memory");
            __builtin_amdgcn_sched_barrier(0);
            __builtin_amdgcn_s_setprio(1);
            if (act0) {
                #pragma unroll
                for (int ni = 0; ni < 4; ++ni) {
                    acc[2*p][ni] = __builtin_amdgcn_mfma_f32_16x16x32_bf16(
                        af[0][0], bf[ni][0], acc[2*p][ni], 0, 0, 0);
                    acc[2*p][ni] = __builtin_amdgcn_mfma_f32_16x16x32_bf16(
                        af[0][1], bf[ni][1], acc[2*p][ni], 0, 0, 0);
                }
            }
            if (act1) {
                #pragma unroll
                for (int ni = 0; ni < 4; ++ni) {
                    acc[2*p+1][ni] = __builtin_amdgcn_mfma_f32_16x16x32_bf16(
                        af[1][0], bf[ni][0], acc[2*p+1][ni], 0, 0, 0);
                    acc[2*p+1][ni] = __builtin_amdgcn_mfma_f32_16x16x32_bf16(
                        af[1][1], bf[ni][1], acc[2*p+1][ni], 0, 0, 0);
                }
            }
            __builtin_amdgcn_s_setprio(0);
            __builtin_amdgcn_sched_barrier(0);
            __builtin_amdgcn_s_barrier();
        }
    };

    // prologue: tile 0 -> buffers 0
    stageB(0, B0);
    loadA(0);
    asm volatile("s_waitcnt vmcnt(0)" ::: "memory");
    writeA(A0);
    asm volatile("s_waitcnt lgkmcnt(0)" ::: "memory");
    __builtin_amdgcn_s_barrier();

    for (int t = 0; t < KTILES; t += 2) {
        tile(t,     A0, B0, A1, B1);
        tile(t + 1, A1, B1, A0, B0);
    }

    // ---- epilogue: bias + leaky + row mask + reduce over rows ----
    float bv[4];
    #pragma unroll
    for (int ni = 0; ni < 4; ++ni) bv[ni] = bias[e0 + wn * 64 + ni * 16 + r16];

    float part[2][4];
    #pragma unroll
    for (int g = 0; g < 2; ++g)
        #pragma unroll
        for (int ni = 0; ni < 4; ++ni) part[g][ni] = 0.f;

    #pragma unroll
    for (int mi = 0; mi < 8; ++mi) {
        const int g = mi >> 2;
        #pragma unroll
        for (int j = 0; j < 4; ++j) {
            const int t = (mi & 3) * 16 + kg * 4 + j;
            if (t < lb[g]) {
                #pragma unroll
                for (int ni = 0; ni < 4; ++ni) {
                    float v = acc[mi][ni][j] + bv[ni];
                    v = v > 0.f ? v : NEG * v;        // leaky before mask (ref order)
                    part[g][ni] += v;
                }
            }
        }
    }
    #pragma unroll
    for (int g = 0; g < 2; ++g)
        #pragma unroll
        for (int ni = 0; ni < 4; ++ni) {
            part[g][ni] += __shfl_xor(part[g][ni], 16, 64);
            part[g][ni] += __shfl_xor(part[g][ni], 32, 64);
        }

    float v0, v1;
    if      (kg == 0) { v0 = part[0][0]; v1 = part[0][1]; }
    else if (kg == 1) { v0 = part[0][2]; v1 = part[0][3]; }
    else if (kg == 2) { v0 = part[1][0]; v1 = part[1][1]; }
    else              { v0 = part[1][2]; v1 = part[1][3]; }
    const int g  = kg >> 1, nh = kg & 1;
    const int batch = bglobal + wm * 2 + g;
    float* orow = out + (size_t)batch * D + e0 + wn * 64 + nh * 32 + r16;
    orow[0]  = scale * v0;
    orow[16] = scale * v1;
}

// 256 blocks: xcd = bid&7 owns 4 cap-mb + 4 img-mb (x all 4 nb, co-resident)
__global__ __launch_bounds__(512, 2)
void vsum_union(const float* __restrict__ cap, const float* __restrict__ img,
                const __bf16* __restrict__ wtb, const __bf16* __restrict__ wib,
                const float* __restrict__ bvt, const float* __restrict__ bvi,
                const int* __restrict__ lens, float scale,
                float* __restrict__ ctxbar, float* __restrict__ vbar)
{
    extern __shared__ __bf16 sm[];
    const int bid = blockIdx.x;
    const int xcd = bid & 7;
    const int j   = bid >> 3;          // 0..31
    const int lcl = j & 15;
    const int mb  = xcd * 4 + (lcl >> 2);
    const int nb  = lcl & 3;
    if (j < 16)
        gemm_body<false>(cap, wtb, bvt, lens,   scale, ctxbar, mb, nb, sm);
    else
        gemm_body<true >(img, wib, bvi, nullptr, scale, vbar,  mb, nb, sm);
}

// sims[i,c] = (g*<ctx_c,cap_c> + <vb_i,cap_c>) /
//             (sqrt(g^2*|ctx_c|^2 + 2g*<ctx_c,vb_i> + |vb_i|^2) + eps)
__global__ __launch_bounds__(256)
void sims_kernel(const float* __restrict__ ctxbar, const float* __restrict__ vbar,
                 const float* __restrict__ capv, const float* __restrict__ gptr,
                 float* __restrict__ out)
{
    constexpr int KC3 = 256;
    __shared__ float Cx[16][KC3 + 4];
    __shared__ float Vb[16][KC3 + 4];
    __shared__ float Cp[16][KC3 + 4];
    const int tid = threadIdx.x;
    const int tx = tid & 15;
    const int ty = tid >> 4;
    const int c0 = blockIdx.x * 16, i0 = blockIdx.y * 16;

    float s1 = 0.f, s2 = 0.f, s3 = 0.f, s4 = 0.f, s5 = 0.f;
    for (int k0 = 0; k0 < D; k0 += KC3) {
        for (int idx = tid; idx < 16 * (KC3 / 4); idx += 256) {
            int row = idx >> 6;
            int k4  = (idx & 63) << 2;
            *(float4*)&Cx[row][k4] = *(const float4*)(ctxbar + (size_t)(c0 + row) * D + k0 + k4);
            *(float4*)&Vb[row][k4] = *(const float4*)(vbar   + (size_t)(i0 + row) * D + k0 + k4);
            *(float4*)&Cp[row][k4] = *(const float4*)(capv   + (size_t)(c0 + row) * D + k0 + k4);
        }
        __syncthreads();
        #pragma unroll 8
        for (int k4 = 0; k4 < KC3 / 4; ++k4) {
            float4 xc = *(const float4*)&Cx[tx][k4 * 4];
            float4 xv = *(const float4*)&Vb[ty][k4 * 4];
            float4 xp = *(const float4*)&Cp[tx][k4 * 4];
            s1 += xc.x * xv.x + xc.y * xv.y + xc.z * xv.z + xc.w * xv.w;
            s2 += xv.x * xp.x + xv.y * xp.y + xv.z * xp.z + xv.w * xp.w;
            s3 += xc.x * xp.x + xc.y * xp.y + xc.z * xp.z + xc.w * xp.w;
            s4 += xc.x * xc.x + xc.y * xc.y + xc.z * xc.z + xc.w * xc.w;
            s5 += xv.x * xv.x + xv.y * xv.y + xv.z * xv.z + xv.w * xv.w;
        }
        __syncthreads();
    }
    const float g = *gptr;
    const float num = g * s3 + s2;
    const float den = sqrtf(g * g * s4 + 2.f * g * s1 + s5) + EPSV;
    out[(size_t)(i0 + ty) * 128 + (c0 + tx)] = num / den;
}

extern "C" void kernel_launch(void* const* d_in, const int* in_sizes, int n_in,
                              void* d_out, int out_size, void* d_ws, size_t ws_size,
                              hipStream_t stream)
{
    const float* img  = (const float*)d_in[0];   // [128,36,1024]
    const float* cap  = (const float*)d_in[1];   // [128,64,1024]
    const int*   lens = (const int*)  d_in[2];   // [128]
    const float* Wvi  = (const float*)d_in[7];   // [1024,1024]
    const float* bvi  = (const float*)d_in[8];
    const float* Wvt  = (const float*)d_in[9];   // [1024,1024]
    const float* bvt  = (const float*)d_in[10];
    const float* gamma = (const float*)d_in[11];
    // Wq/bq/Wk/bk/alpha/beta dead: softmax then mean over same axis == 1/R.

    float* out = (float*)d_out;

    // ws: wtb 2M | wib 2M | ctxbar .5 | vbar .5 | capv .5 | cappart 2M  (7.5 MB)
    __bf16* wtb = (__bf16*)d_ws;
    __bf16* wib = wtb + (size_t)1024 * 1024;
    float* ctxbar  = (float*)(wib + (size_t)1024 * 1024);
    float* vbar    = ctxbar + 128 * 1024;
    float* capv    = vbar   + 128 * 1024;
    float* cappart = capv   + 128 * 1024;        // 4*128*1024

    const float scale = 1.f / 36.f;      // attn_mean == 1/R exactly; also v_img mean
    dim3 blk(256);

    hipFuncSetAttribute((const void*)vsum_union,
                        hipFuncAttributeMaxDynamicSharedMemorySize, 131072);

    convert_wcap<<<dim3(1536), blk, 0, stream>>>(Wvt, Wvi, cap, lens, wtb, wib, cappart);
    capfin<<<dim3(128), blk, 0, stream>>>(cappart, lens, capv);
    vsum_union<<<dim3(256), dim3(512), 131072, stream>>>(cap, img, wtb, wib,
                                                         bvt, bvi, lens, scale,
                                                         ctxbar, vbar);
    sims_kernel<<<dim3(8, 8), blk, 0, stream>>>(ctxbar, vbar, capv, gamma, out);
}